// Round 8
// baseline (846.519 us; speedup 1.0000x reference)
//
#include <hip/hip_runtime.h>
#include <cstddef>
#include <cstdint>

#define VOCAB  32000
#define EMB    256
#define NB     8
#define KDIM   2048        /* H*NB */
#define NROWS  1024        /* B*L  */
#define NCOL   4096        /* 2*KDIM */
#define LLEN   256

typedef __attribute__((ext_vector_type(8))) short short8;
typedef __attribute__((ext_vector_type(4))) float f32x4;
typedef __attribute__((ext_vector_type(16))) float f32x16;
typedef __attribute__((ext_vector_type(4))) int i32x4;
typedef __attribute__((ext_vector_type(16))) int i32x16;

__device__ __forceinline__ float cl3_sign(int a, int b) {
  int x = a >> 1, p = 0;
  while (x) { p ^= __popc(x & b) & 1; x >>= 1; }
  return p ? -1.f : 1.f;   // metric all +1 for Cl(3,0)
}

__device__ __forceinline__ float clipf(float v) { return fminf(fmaxf(v, 0.f), 1.f); }

__device__ __forceinline__ unsigned short f2bf(float f) {
  unsigned u = __float_as_uint(f);
  u += 0x7FFF + ((u >> 16) & 1);           // round-to-nearest-even
  return (unsigned short)(u >> 16);
}
__device__ __forceinline__ float bf2f(unsigned short h) {
  return __uint_as_float(((unsigned)h) << 16);
}

__device__ __forceinline__ void gload16(const void* g, void* l) {
  __builtin_amdgcn_global_load_lds((const __attribute__((address_space(1))) uint32_t*)g,
                                   (__attribute__((address_space(3))) uint32_t*)l, 16, 0, 0);
}

// scale: s = 2^(ilogb(max)+2); inv = 128/s; digits in [-64,64]
__device__ __forceinline__ float dig_inv(float mx) {
  return exp2f((float)(5 - ilogbf(fmaxf(mx, 1e-20f))));
}

// bf16 plane layout: [tiles(128r x 16k)][2 chunk(8k)][128 row][8 elem]  (2048 ush = 4KB per slab)
// slab index = rowtile*128 + kt16
__device__ __forceinline__ size_t bfoff(int rt, int k, int r) {
  return ((size_t)(rt * 128 + (k >> 4)) << 11) + (size_t)(((k >> 3) & 1) << 10) + ((r & 127) << 3) + (k & 7);
}

// ---- MRT split build: B^T [4096][2048] -> slab-tiled hi/lo bf16 ----
__global__ void k_build_mrt_split(const float* __restrict__ Wrec,
                                  unsigned short* __restrict__ Mhi,
                                  unsigned short* __restrict__ Mlo) {
  int idx = blockIdx.x * blockDim.x + threadIdx.x;
  int k = idx & (KDIM - 1);
  int n = idx >> 11;
  int h = k >> 3, i = k & 7;
  float v;
  if (n < KDIM) {
    int g = n >> 3, kb = n & 7;
    int j = i ^ kb;
    v = Wrec[(size_t)g * KDIM + h * NB + j] * cl3_sign(i, j);
  } else {
    int c = n - KDIM;
    int p = c >> 3, q = c & 7;
    int j = q ^ i;
    v = cl3_sign(i, i) * cl3_sign(q, j) * Wrec[(size_t)h * KDIM + p * NB + j];
  }
  unsigned short hi = f2bf(v);
  unsigned short lo = f2bf(v - bf2f(hi));
  size_t off = bfoff(n >> 7, k, n);
  Mhi[off] = hi; Mlo[off] = lo;
}

// ---- Wout digitizer, fused per-row scale: block = 32 vocab rows, 8 thr/row ----
// i8 plane layout: [tiles(128r x 32k)][2 kq(16k)][128 row][16 elem] (4KB per slab)
__global__ __launch_bounds__(256) void k_dig_wout(const float* __restrict__ W,
                                                  float* __restrict__ sB,
                                                  char* __restrict__ Wd1,
                                                  char* __restrict__ Wd2) {
  const int t = threadIdx.x;
  const int row = blockIdx.x * 32 + (t >> 3);
  const int g = t & 7;
  const float* src = W + (size_t)row * KDIM + g * 256;
  float m = 0.f;
#pragma unroll 8
  for (int q = 0; q < 64; ++q) {
    float4 v = *(const float4*)(src + q * 4);
    m = fmaxf(m, fmaxf(fmaxf(fabsf(v.x), fabsf(v.y)), fmaxf(fabsf(v.z), fabsf(v.w))));
  }
  m = fmaxf(m, __shfl_xor(m, 1));
  m = fmaxf(m, __shfl_xor(m, 2));
  m = fmaxf(m, __shfl_xor(m, 4));
  m = fmaxf(m, 1e-20f);
  if (g == 0) sB[row] = exp2f((float)(ilogbf(m) + 2));
  const float inv = dig_inv(m);
  const int tn = row >> 7, rowin = row & 127;
  for (int q = 0; q < 32; ++q) {
    int c = g * 256 + q * 8;
    float e[8];
    *(float4*)&e[0] = *(const float4*)(src + q * 8);
    *(float4*)&e[4] = *(const float4*)(src + q * 8 + 4);
    char d1[8], d2[8];
#pragma unroll
    for (int j = 0; j < 8; ++j) {
      float tv = e[j] * inv;
      float f1 = rintf(tv);
      d1[j] = (char)(int)f1;
      d2[j] = (char)(int)rintf((tv - f1) * 128.f);
    }
    size_t addr = ((size_t)(tn * 64 + (c >> 5)) << 12) + (size_t)(((c >> 4) & 1) << 11)
                + (rowin << 4) + (c & 15);
    *(uint64_t*)&Wd1[addr] = *(uint64_t*)d1;
    *(uint64_t*)&Wd2[addr] = *(uint64_t*)d2;
  }
}

// input_mv[r][h*8+i] = sum_d emb[x[r]][d] * Win[h][d][i]; one block = 4 rows
__global__ __launch_bounds__(256) void k_input_mv(const int* __restrict__ x,
                                                  const float* __restrict__ emb,
                                                  const float* __restrict__ Win,
                                                  float* __restrict__ out) {
  __shared__ float se[4][EMB];
  int r0 = blockIdx.x * 4;
  int t = threadIdx.x;
  for (int rr = 0; rr < 4; ++rr) {
    int tok = x[r0 + rr];
    se[rr][t] = emb[(size_t)tok * EMB + t];
  }
  __syncthreads();
  float acc[4][8];
#pragma unroll
  for (int rr = 0; rr < 4; ++rr)
#pragma unroll
    for (int i = 0; i < 8; ++i) acc[rr][i] = 0.f;
  const float* wrow = Win + (size_t)t * KDIM;
  for (int d = 0; d < EMB; ++d) {
    float4 w0 = *(const float4*)(wrow + d * 8);
    float4 w1 = *(const float4*)(wrow + d * 8 + 4);
#pragma unroll
    for (int rr = 0; rr < 4; ++rr) {
      float e = se[rr][d];
      acc[rr][0] += e * w0.x; acc[rr][1] += e * w0.y;
      acc[rr][2] += e * w0.z; acc[rr][3] += e * w0.w;
      acc[rr][4] += e * w1.x; acc[rr][5] += e * w1.y;
      acc[rr][6] += e * w1.z; acc[rr][7] += e * w1.w;
    }
  }
  for (int rr = 0; rr < 4; ++rr) {
    float4* o = (float4*)(out + (size_t)(r0 + rr) * KDIM + t * 8);
    o[0] = make_float4(acc[rr][0], acc[rr][1], acc[rr][2], acc[rr][3]);
    o[1] = make_float4(acc[rr][4], acc[rr][5], acc[rr][6], acc[rr][7]);
  }
}

// ---- free-phase bf16 split GEMM: 4 waves, 128x128 tile, BK=16, 3x16KB buffers ----
// split-K x2 (halves -> RF0/RF1). Per-acc MFMA order identical to prior rounds
// (16-k groups ascending, hh->hl->lh) => bit-identical trajectory.
__global__ __launch_bounds__(256, 2) void k_gemm_pre(const unsigned short* __restrict__ Ahi,
                                                     const unsigned short* __restrict__ Alo,
                                                     const unsigned short* __restrict__ Bhi,
                                                     const unsigned short* __restrict__ Blo,
                                                     float* __restrict__ RF0,
                                                     float* __restrict__ RF1) {
  __shared__ __align__(16) char lds[3 * 16384];   // 3 x {Ahi 4K | Alo 4K | Bhi 4K | Blo 4K}
  const int b = blockIdx.x;                        // 512 blocks
  const int lin = (b & 7) * 64 + (b >> 3);         // XCD-chunked (512 % 8 == 0)
  const int half = lin >> 8;
  const int rest = lin & 255;
  const int tm = rest & 7, tn = rest >> 3;         // tn 0..31; 8 consecutive lin share B panel
  const int ktbase = half * 64;                    // kt16 units
  float* __restrict__ C = half ? RF1 : RF0;
  const int t = threadIdx.x;
  const int l = t & 63, w = t >> 6;
  const int wr = w >> 1, wc = w & 1;

  const char* aHg = (const char*)Ahi + (((size_t)tm * 128 + ktbase) << 12) + (t << 4);
  const char* aLg = (const char*)Alo + (((size_t)tm * 128 + ktbase) << 12) + (t << 4);
  const char* bHg = (const char*)Bhi + (((size_t)tn * 128 + ktbase) << 12) + (t << 4);
  const char* bLg = (const char*)Blo + (((size_t)tn * 128 + ktbase) << 12) + (t << 4);
  const int wo = w << 10;

  f32x16 acc[2][2];
#pragma unroll
  for (int i = 0; i < 2; ++i)
#pragma unroll
    for (int j = 0; j < 2; ++j) acc[i][j] = (f32x16)0.f;

  auto STAGE = [&](int bf, int kt) {
    char* lb = &lds[bf * 16384];
    size_t kb = (size_t)kt << 12;
    gload16(aHg + kb, lb + wo);
    gload16(aLg + kb, lb + 4096 + wo);
    gload16(bHg + kb, lb + 8192 + wo);
    gload16(bLg + kb, lb + 12288 + wo);
  };

  STAGE(0, 0); STAGE(1, 1);

  const int ra = wr * 64 + (l & 31);
  const int rb = wc * 64 + (l & 31);
  const int cho = (l >> 5) << 11;                  // chunk byte offset within plane
  int cur = 0;
  for (int kt = 0; kt < 64; ++kt) {
    int pf = cur + 2; if (pf >= 3) pf -= 3;
    if (kt < 63) { asm volatile("s_waitcnt vmcnt(4)" ::: "memory"); }
    else         { asm volatile("s_waitcnt vmcnt(0)" ::: "memory"); }
    __builtin_amdgcn_s_barrier();
    const char* lb = &lds[cur * 16384];
    short8 ah[2], al[2], bh[2], bl[2];
#pragma unroll
    for (int mi = 0; mi < 2; ++mi) {
      int off = cho + ((ra + mi * 32) << 4);
      ah[mi] = *(const short8*)(lb + off);
      al[mi] = *(const short8*)(lb + 4096 + off);
    }
#pragma unroll
    for (int nj = 0; nj < 2; ++nj) {
      int off = cho + ((rb + nj * 32) << 4);
      bh[nj] = *(const short8*)(lb + 8192 + off);
      bl[nj] = *(const short8*)(lb + 12288 + off);
    }
    if (kt + 2 < 64) STAGE(pf, kt + 2);
    __builtin_amdgcn_s_setprio(1);
#pragma unroll
    for (int mi = 0; mi < 2; ++mi)
#pragma unroll
      for (int nj = 0; nj < 2; ++nj) {
        acc[mi][nj] = __builtin_amdgcn_mfma_f32_32x32x16_bf16(ah[mi], bh[nj], acc[mi][nj], 0, 0, 0);
        acc[mi][nj] = __builtin_amdgcn_mfma_f32_32x32x16_bf16(ah[mi], bl[nj], acc[mi][nj], 0, 0, 0);
        acc[mi][nj] = __builtin_amdgcn_mfma_f32_32x32x16_bf16(al[mi], bh[nj], acc[mi][nj], 0, 0, 0);
      }
    __builtin_amdgcn_s_setprio(0);
    cur = (cur == 2) ? 0 : cur + 1;
  }

  const int rg0 = tm * 128 + wr * 64 + ((l >> 5) << 2);
  const int cg0 = tn * 128 + wc * 64 + (l & 31);
#pragma unroll
  for (int mi = 0; mi < 2; ++mi)
#pragma unroll
    for (int nj = 0; nj < 2; ++nj) {
      f32x16 v = acc[mi][nj];
#pragma unroll
      for (int g = 0; g < 16; ++g) {
        int rr = (g & 3) + ((g >> 2) << 3);
        C[(size_t)(rg0 + mi * 32 + rr) * NCOL + cg0 + nj * 32] = v[g];
      }
    }
}

// ---- i8 digit GEMM (logits): 4 waves, 128x128 tile, BK=32, 3x16KB buffers ----
__global__ __launch_bounds__(256, 2) void k_gemm_i8(const char* __restrict__ Ad1,
                                                    const char* __restrict__ Ad2,
                                                    const char* __restrict__ Bd1,
                                                    const char* __restrict__ Bd2,
                                                    const float* __restrict__ sA,
                                                    const float* __restrict__ sB,
                                                    float* __restrict__ C) {
  __shared__ __align__(16) char lds[3 * 16384];   // 3 x {A1 4K | A2 4K | B1 4K | B2 4K}
  const int b = blockIdx.x;                       // 2000 blocks
  const int lin = (b & 7) * 250 + (b >> 3);       // XCD-chunked (2000 % 8 == 0)
  const int tm = lin & 7, tn = lin >> 3;          // tn 0..249
  const int t = threadIdx.x;
  const int l = t & 63, w = t >> 6;
  const int wr = w >> 1, wc = w & 1;

  const char* a1g = Ad1 + (((size_t)tm * 64) << 12) + (t << 4);
  const char* a2g = Ad2 + (((size_t)tm * 64) << 12) + (t << 4);
  const char* b1g = Bd1 + (((size_t)tn * 64) << 12) + (t << 4);
  const char* b2g = Bd2 + (((size_t)tn * 64) << 12) + (t << 4);
  const int wo = w << 10;

  i32x16 acc1[2][2], acc2[2][2];
#pragma unroll
  for (int i = 0; i < 2; ++i)
#pragma unroll
    for (int j = 0; j < 2; ++j) { acc1[i][j] = (i32x16)0; acc2[i][j] = (i32x16)0; }

  auto STAGE = [&](int bf, int kt) {
    char* lb = &lds[bf * 16384];
    size_t kb = (size_t)kt << 12;
    gload16(a1g + kb, lb + wo);
    gload16(a2g + kb, lb + 4096 + wo);
    gload16(b1g + kb, lb + 8192 + wo);
    gload16(b2g + kb, lb + 12288 + wo);
  };

  STAGE(0, 0); STAGE(1, 1);

  const int ra = wr * 64 + (l & 31);
  const int rb = wc * 64 + (l & 31);
  const int kqo = (l >> 5) << 11;                 // kq byte offset within plane
  int cur = 0;
  for (int kt = 0; kt < 64; ++kt) {
    int pf = cur + 2; if (pf >= 3) pf -= 3;
    if (kt < 63) { asm volatile("s_waitcnt vmcnt(4)" ::: "memory"); }
    else         { asm volatile("s_waitcnt vmcnt(0)" ::: "memory"); }
    __builtin_amdgcn_s_barrier();
    const char* lb = &lds[cur * 16384];
    i32x4 a1[2], a2[2], b1[2], b2[2];
#pragma unroll
    for (int mi = 0; mi < 2; ++mi) {
      int off = kqo + ((ra + mi * 32) << 4);
      a1[mi] = *(const i32x4*)(lb + off);
      a2[mi] = *(const i32x4*)(lb + 4096 + off);
    }
#pragma unroll
    for (int nj = 0; nj < 2; ++nj) {
      int off = kqo + ((rb + nj * 32) << 4);
      b1[nj] = *(const i32x4*)(lb + 8192 + off);
      b2[nj] = *(const i32x4*)(lb + 12288 + off);
    }
    if (kt + 2 < 64) STAGE(pf, kt + 2);
    __builtin_amdgcn_s_setprio(1);
#pragma unroll
    for (int mi = 0; mi < 2; ++mi)
#pragma unroll
      for (int nj = 0; nj < 2; ++nj) {
        acc1[mi][nj] = __builtin_amdgcn_mfma_i32_32x32x32_i8(a1[mi], b1[nj], acc1[mi][nj], 0, 0, 0);
        acc2[mi][nj] = __builtin_amdgcn_mfma_i32_32x32x32_i8(a1[mi], b2[nj], acc2[mi][nj], 0, 0, 0);
        acc2[mi][nj] = __builtin_amdgcn_mfma_i32_32x32x32_i8(a2[mi], b1[nj], acc2[mi][nj], 0, 0, 0);
      }
    __builtin_amdgcn_s_setprio(0);
    cur = (cur == 2) ? 0 : cur + 1;
  }

  const int rbase = tm * 128 + wr * 64 + ((l >> 5) << 2);
  const int cb = tn * 128 + wc * 64 + (l & 31);
#pragma unroll
  for (int mi = 0; mi < 2; ++mi)
#pragma unroll
    for (int nj = 0; nj < 2; ++nj) {
      float sBv = sB[cb + nj * 32] * (1.f / 16384.f);
#pragma unroll
      for (int g = 0; g < 16; ++g) {
        int rr = (g & 3) + ((g >> 2) << 3);
        int row = rbase + mi * 32 + rr;
        float c1 = sA[row] * sBv;
        C[(size_t)row * VOCAB + cb + nj * 32] =
            fmaf((float)acc2[mi][nj][g], c1 * (1.f / 128.f), (float)acc1[mi][nj][g] * c1);
      }
    }
}

// h <- h - 0.1*(h - drho(h)*(inmv*sq + rec_prev*sq + fwd_next))
// LAST=0: emit bf16 hi/lo planes; LAST=1: per-row scale + i8 digits (block = one row)
template <int LAST>
__global__ __launch_bounds__(256) void k_update(float* __restrict__ Hb, const float* __restrict__ Imv,
                                                const float* __restrict__ RF0, const float* __restrict__ RF1,
                                                unsigned short* __restrict__ Hhi,
                                                unsigned short* __restrict__ Hlo,
                                                float* __restrict__ sA,
                                                char* __restrict__ Ad1,
                                                char* __restrict__ Ad2,
                                                int big) {
  __shared__ float red[256];
  int tix = threadIdx.x;
  int idx = blockIdx.x * 256 + tix;
  int r = idx >> 8;
  int c = (idx & 255) << 3;
  int m = r & (LLEN - 1);
  const size_t base = (size_t)r * KDIM + c;
  float h[8], f[8];
  *(float4*)&h[0] = *(const float4*)(Hb + base);
  *(float4*)&h[4] = *(const float4*)(Hb + base + 4);
  float4 i0 = *(const float4*)(Imv + base);
  float4 i1 = *(const float4*)(Imv + base + 4);
  f[0] = i0.x; f[1] = i0.y; f[2] = i0.z; f[3] = i0.w;
  f[4] = i1.x; f[5] = i1.y; f[6] = i1.z; f[7] = i1.w;
#pragma unroll
  for (int j = 0; j < 8; ++j) f[j] *= ((0xE8 >> j) & 1) ? -1.f : 1.f;
  if (m >= 1) {
    const float* rp0 = RF0 + (size_t)(r - 1) * NCOL + c;
    const float* rp1 = RF1 + (size_t)(r - 1) * NCOL + c;
#pragma unroll
    for (int j = 0; j < 8; ++j)
      f[j] += (rp0[j] + rp1[j]) * (((0xE8 >> j) & 1) ? -1.f : 1.f);
  }
  if (m < LLEN - 1) {
    const float* rn0 = RF0 + (size_t)(r + 1) * NCOL + KDIM + c;
    const float* rn1 = RF1 + (size_t)(r + 1) * NCOL + KDIM + c;
#pragma unroll
    for (int j = 0; j < 8; ++j) f[j] += rn0[j] + rn1[j];
  }
  float hn[8], av[8];
#pragma unroll
  for (int j = 0; j < 8; ++j) {
    float hv = h[j];
    float dr = (hv > 0.f && hv < 1.f) ? 1.f : ((hv == 0.f || hv == 1.f) ? 0.5f : 0.f);
    hn[j] = hv - 0.1f * (hv - dr * f[j]);
  }
  *(float4*)(Hb + base) = make_float4(hn[0], hn[1], hn[2], hn[3]);
  *(float4*)(Hb + base + 4) = make_float4(hn[4], hn[5], hn[6], hn[7]);
  if (!LAST) {
    short8 h8, l8;
#pragma unroll
    for (int j = 0; j < 8; ++j) {
      float a = clipf(hn[j]);
      unsigned short hi = f2bf(a);
      h8[j] = (short)hi;
      l8[j] = (short)f2bf(a - bf2f(hi));
    }
    size_t off = bfoff(r >> 7, c, r);
    *(short8*)&Hhi[off] = h8;
    *(short8*)&Hlo[off] = l8;
  } else {
    if (!big) return;
#pragma unroll
    for (int j = 0; j < 8; ++j) av[j] = hn[j] * (((0xE8 >> j) & 1) ? -1.f : 1.f);
    float lm = 0.f;
#pragma unroll
    for (int j = 0; j < 8; ++j) lm = fmaxf(lm, fabsf(av[j]));
    red[tix] = lm; __syncthreads();
    for (int s = 128; s; s >>= 1) { if (tix < s) red[tix] = fmaxf(red[tix], red[tix + s]); __syncthreads(); }
    float mx = fmaxf(red[0], 1e-20f);
    float inv = dig_inv(mx);
    if (tix == 0) sA[r] = exp2f((float)(ilogbf(mx) + 2));
    char d1[8], d2[8];
#pragma unroll
    for (int j = 0; j < 8; ++j) {
      float tv = av[j] * inv;
      float f1 = rintf(tv);
      d1[j] = (char)(int)f1;
      d2[j] = (char)(int)rintf((tv - f1) * 128.f);
    }
    // i8 A layout: [tiles(128r x 32k)][2 kq][128 row][16]
    size_t addr = ((size_t)((r >> 7) * 64 + (c >> 5)) << 12) + (size_t)(((c >> 4) & 1) << 11)
                + ((r & 127) << 4) + (c & 15);
    *(uint64_t*)&Ad1[addr] = *(uint64_t*)d1;
    *(uint64_t*)&Ad2[addr] = *(uint64_t*)d2;
  }
}

// ---- fallback logits GEMM (in-kernel bf16 conversion), used if ws too small ----
template <int AMODE>
__global__ __launch_bounds__(256) void k_gemm_split(const float* __restrict__ A,
                                                    const float* __restrict__ B,
                                                    float* __restrict__ C, int ldc) {
  __shared__ unsigned short Ah[128 * 32], Al[128 * 32];
  __shared__ unsigned short Bh[128 * 32], Bl[128 * 32];
  const int t = threadIdx.x;
  const int row0 = blockIdx.y * 128, col0 = blockIdx.x * 128;
  const int l = t & 63, w = t >> 6;
  const int wr = w >> 1, wc = w & 1;
  const int sr = t >> 3;
  const int cc = (t & 7) << 2;
  const int chunkb = cc >> 3;
  const int halfo = (cc >> 2) & 1;
  f32x4 acc[4][4];
#pragma unroll
  for (int i = 0; i < 4; ++i)
#pragma unroll
    for (int j = 0; j < 4; ++j) acc[i][j] = (f32x4)0.f;
  const float sA0 = 1.f;
  const float sA1 = (cc & 4) ? -1.f : 1.f;
  const float sA2 = sA1;
  const float sA3 = -1.f;
  for (int k0 = 0; k0 < KDIM; k0 += 32) {
    float4 va[4], vb[4];
#pragma unroll
    for (int i = 0; i < 4; ++i) {
      va[i] = *(const float4*)(A + (size_t)(row0 + sr + i * 32) * KDIM + k0 + cc);
      vb[i] = *(const float4*)(B + (size_t)(col0 + sr + i * 32) * KDIM + k0 + cc);
    }
    __syncthreads();
#pragma unroll
    for (int i = 0; i < 4; ++i) {
      int row = sr + i * 32;
      int idx = row * 32 + ((chunkb ^ (row & 3)) << 3) + (halfo << 2);
      float4 a = va[i];
      if (AMODE == 0) {
        a.x = clipf(a.x); a.y = clipf(a.y); a.z = clipf(a.z); a.w = clipf(a.w);
      } else {
        a.x *= sA0; a.y *= sA1; a.z *= sA2; a.w *= sA3;
      }
      ushort4 h4, l4;
      h4.x = f2bf(a.x); l4.x = f2bf(a.x - bf2f(h4.x));
      h4.y = f2bf(a.y); l4.y = f2bf(a.y - bf2f(h4.y));
      h4.z = f2bf(a.z); l4.z = f2bf(a.z - bf2f(h4.z));
      h4.w = f2bf(a.w); l4.w = f2bf(a.w - bf2f(h4.w));
      *(ushort4*)&Ah[idx] = h4;
      *(ushort4*)&Al[idx] = l4;
      float4 bb = vb[i];
      h4.x = f2bf(bb.x); l4.x = f2bf(bb.x - bf2f(h4.x));
      h4.y = f2bf(bb.y); l4.y = f2bf(bb.y - bf2f(h4.y));
      h4.z = f2bf(bb.z); l4.z = f2bf(bb.z - bf2f(h4.z));
      h4.w = f2bf(bb.w); l4.w = f2bf(bb.w - bf2f(h4.w));
      *(ushort4*)&Bh[idx] = h4;
      *(ushort4*)&Bl[idx] = l4;
    }
    __syncthreads();
    short8 ah[4], al[4], bh[4], bl[4];
#pragma unroll
    for (int mi = 0; mi < 4; ++mi) {
      int ar = wr * 64 + mi * 16 + (l & 15);
      int kc = (l >> 4) ^ (ar & 3);
      ah[mi] = *(short8*)&Ah[ar * 32 + kc * 8];
      al[mi] = *(short8*)&Al[ar * 32 + kc * 8];
      int br = wc * 64 + mi * 16 + (l & 15);
      int kb = (l >> 4) ^ (br & 3);
      bh[mi] = *(short8*)&Bh[br * 32 + kb * 8];
      bl[mi] = *(short8*)&Bl[br * 32 + kb * 8];
    }
#pragma unroll
    for (int mi = 0; mi < 4; ++mi)
#pragma unroll
      for (int ni = 0; ni < 4; ++ni) {
        acc[mi][ni] = __builtin_amdgcn_mfma_f32_16x16x32_bf16(ah[mi], bh[ni], acc[mi][ni], 0, 0, 0);
        acc[mi][ni] = __builtin_amdgcn_mfma_f32_16x16x32_bf16(ah[mi], bl[ni], acc[mi][ni], 0, 0, 0);
        acc[mi][ni] = __builtin_amdgcn_mfma_f32_16x16x32_bf16(al[mi], bh[ni], acc[mi][ni], 0, 0, 0);
      }
  }
#pragma unroll
  for (int mi = 0; mi < 4; ++mi)
#pragma unroll
    for (int ni = 0; ni < 4; ++ni) {
      int rg = row0 + wr * 64 + mi * 16 + (l >> 4) * 4;
      int cg = col0 + wc * 64 + ni * 16 + (l & 15);
#pragma unroll
      for (int j = 0; j < 4; ++j)
        C[(size_t)(rg + j) * ldc + cg] = acc[mi][ni][j];
    }
}

extern "C" void kernel_launch(void* const* d_in, const int* in_sizes, int n_in,
                              void* d_out, int out_size, void* d_ws, size_t ws_size,
                              hipStream_t stream) {
  const int*   x    = (const int*)d_in[0];
  const float* emb  = (const float*)d_in[1];
  const float* Win  = (const float*)d_in[2];
  const float* Wrec = (const float*)d_in[3];
  const float* Wout = (const float*)d_in[4];
  float* logits = (float*)d_out;

  char* base = (char*)d_ws;
  const size_t MB = 1ull << 20;
  float* Hbuf = (float*)(base + 0);
  float* Imv  = (float*)(base + 8 * MB);
  float* RF0  = (float*)(base + 16 * MB);
  float* RF1  = (float*)(base + 32 * MB);
  unsigned short* Hhi = (unsigned short*)(base + 48 * MB);
  unsigned short* Hlo = (unsigned short*)(base + 52 * MB);
  unsigned short* Mhi = (unsigned short*)(base + 56 * MB);
  unsigned short* Mlo = (unsigned short*)(base + 72 * MB);
  float* sA  = (float*)(base + 88 * MB);                       // 4 KB
  float* sB  = (float*)(base + 88 * MB + 4096);                // 128 KB
  char* Wd1  = base + 88 * MB + 160 * 1024;
  char* Wd2  = Wd1 + (size_t)VOCAB * KDIM;
  // A digits reuse the MRT space (MRT last read by final k_gemm_pre, before k_update<1>)
  char* Ad1  = (char*)Mhi;
  char* Ad2  = (char*)Mlo;

  const size_t need = (size_t)(Wd2 - base) + (size_t)VOCAB * KDIM;
  const bool big = ws_size >= need;

  hipMemsetAsync(Hbuf, 0, 8 * MB, stream);
  hipMemsetAsync(Hhi, 0, 8 * MB, stream);          // Hhi+Hlo contiguous
  k_build_mrt_split<<<32768, 256, 0, stream>>>(Wrec, Mhi, Mlo);
  k_input_mv<<<256, 256, 0, stream>>>(x, emb, Win, Imv);
  if (big) {
    k_dig_wout<<<1000, 256, 0, stream>>>(Wout, sB, Wd1, Wd2);
  }

  for (int it = 0; it < 5; ++it) {
    k_gemm_pre<<<512, 256, 0, stream>>>(Hhi, Hlo, Mhi, Mlo, RF0, RF1);
    if (it < 4) k_update<0><<<1024, 256, 0, stream>>>(Hbuf, Imv, RF0, RF1, Hhi, Hlo, sA, Ad1, Ad2, big);
    else        k_update<1><<<1024, 256, 0, stream>>>(Hbuf, Imv, RF0, RF1, Hhi, Hlo, sA, Ad1, Ad2, big);
  }

  if (big) {
    k_gemm_i8<<<2000, 256, 0, stream>>>(Ad1, Ad2, Wd1, Wd2, sA, sB, logits);
  } else {
    k_gemm_split<1><<<dim3(VOCAB / 128, NROWS / 128), 256, 0, stream>>>(Hbuf, Wout, logits, VOCAB);
  }
}

// Round 9
// 631.199 us; speedup vs baseline: 1.3411x; 1.3411x over previous
//
#include <hip/hip_runtime.h>
#include <cstddef>
#include <cstdint>

#define VOCAB  32000
#define EMB    256
#define NB     8
#define KDIM   2048        /* H*NB */
#define NROWS  1024        /* B*L  */
#define NCOL   4096        /* 2*KDIM */
#define LLEN   256

typedef __attribute__((ext_vector_type(8))) short short8;
typedef __attribute__((ext_vector_type(4))) float f32x4;
typedef __attribute__((ext_vector_type(16))) float f32x16;
typedef __attribute__((ext_vector_type(4))) int i32x4;
typedef __attribute__((ext_vector_type(16))) int i32x16;

__device__ __forceinline__ float cl3_sign(int a, int b) {
  int x = a >> 1, p = 0;
  while (x) { p ^= __popc(x & b) & 1; x >>= 1; }
  return p ? -1.f : 1.f;   // metric all +1 for Cl(3,0)
}

__device__ __forceinline__ float clipf(float v) { return fminf(fmaxf(v, 0.f), 1.f); }

__device__ __forceinline__ unsigned short f2bf(float f) {
  unsigned u = __float_as_uint(f);
  u += 0x7FFF + ((u >> 16) & 1);           // round-to-nearest-even
  return (unsigned short)(u >> 16);
}
__device__ __forceinline__ float bf2f(unsigned short h) {
  return __uint_as_float(((unsigned)h) << 16);
}

__device__ __forceinline__ void gload16(const void* g, void* l) {
  __builtin_amdgcn_global_load_lds((const __attribute__((address_space(1))) uint32_t*)g,
                                   (__attribute__((address_space(3))) uint32_t*)l, 16, 0, 0);
}

// scale: s = 2^(ilogb(max)+2); inv = 128/s; digits in [-64,64]
__device__ __forceinline__ float dig_inv(float mx) {
  return exp2f((float)(5 - ilogbf(fmaxf(mx, 1e-20f))));
}

// bf16 plane layout: [tiles(128r x 16k)][2 chunk(8k)][128 row][8 elem]  (2048 ush = 4KB per slab)
__device__ __forceinline__ size_t bfoff(int rt, int k, int r) {
  return ((size_t)(rt * 128 + (k >> 4)) << 11) + (size_t)(((k >> 3) & 1) << 10) + ((r & 127) << 3) + (k & 7);
}

// ---- MRT split build: B^T [4096][2048] -> slab-tiled hi/lo bf16 ----
__global__ void k_build_mrt_split(const float* __restrict__ Wrec,
                                  unsigned short* __restrict__ Mhi,
                                  unsigned short* __restrict__ Mlo) {
  int idx = blockIdx.x * blockDim.x + threadIdx.x;
  int k = idx & (KDIM - 1);
  int n = idx >> 11;
  int h = k >> 3, i = k & 7;
  float v;
  if (n < KDIM) {
    int g = n >> 3, kb = n & 7;
    int j = i ^ kb;
    v = Wrec[(size_t)g * KDIM + h * NB + j] * cl3_sign(i, j);
  } else {
    int c = n - KDIM;
    int p = c >> 3, q = c & 7;
    int j = q ^ i;
    v = cl3_sign(i, i) * cl3_sign(q, j) * Wrec[(size_t)h * KDIM + p * NB + j];
  }
  unsigned short hi = f2bf(v);
  unsigned short lo = f2bf(v - bf2f(hi));
  size_t off = bfoff(n >> 7, k, n);
  Mhi[off] = hi; Mlo[off] = lo;
}

// ---- Wout digitizer, single-pass, LDS-staged: block = 4 vocab rows ----
// i8 plane layout: [tiles(128r x 32k)][2 kq(16k)][128 row][16 elem] (4KB per slab)
__global__ __launch_bounds__(256) void k_dig_wout(const float* __restrict__ W,
                                                  float* __restrict__ sB,
                                                  char* __restrict__ Wd1,
                                                  char* __restrict__ Wd2) {
  __shared__ float ld[4 * 2052];
  __shared__ float rmax[4];
  const int t = threadIdx.x;
  const int bid = blockIdx.x;               // 8000 blocks
  const float* src = W + (size_t)bid * 8192;
  // phase 1: fully coalesced load into LDS (row stride padded to 2052 floats)
#pragma unroll
  for (int i = 0; i < 8; ++i) {
    int f = i * 256 + t;                    // float4 index 0..2047
    int row = f >> 9, c4 = f & 511;
    float4 v = ((const float4*)src)[f];
    *(float4*)&ld[row * 2052 + c4 * 4] = v;
  }
  __syncthreads();
  // phase 2: per-wave row max (wave w owns row w)
  const int w = t >> 6, l = t & 63;
  float m = 0.f;
#pragma unroll
  for (int j = 0; j < 8; ++j) {
    float4 v = *(const float4*)&ld[w * 2052 + (j * 64 + l) * 4];
    m = fmaxf(m, fmaxf(fmaxf(fabsf(v.x), fabsf(v.y)), fmaxf(fabsf(v.z), fabsf(v.w))));
  }
#pragma unroll
  for (int s = 1; s < 64; s <<= 1) m = fmaxf(m, __shfl_xor(m, s));
  m = fmaxf(m, 1e-20f);
  if (l == 0) { rmax[w] = m; sB[bid * 4 + w] = exp2f((float)(ilogbf(m) + 2)); }
  __syncthreads();
  // phase 3: digitize; 4 lanes (rows) x 16B = 64B contiguous write segments
  const int rloc = t & 3;
  const int rowg = bid * 4 + rloc;
  const int rowtile = rowg >> 7, rowin = rowg & 127;
  const float inv = dig_inv(rmax[rloc]);
#pragma unroll
  for (int it = 0; it < 2; ++it) {
    int c16 = (t >> 2) + it * 64;           // 0..127
    char d1[16], d2[16];
#pragma unroll
    for (int j = 0; j < 16; ++j) {
      float tv = ld[rloc * 2052 + c16 * 16 + j] * inv;
      float f1 = rintf(tv);
      d1[j] = (char)(int)f1;
      d2[j] = (char)(int)rintf((tv - f1) * 128.f);
    }
    size_t addr = ((size_t)(rowtile * 64 + (c16 >> 1)) << 12) + (size_t)((c16 & 1) << 11) + (rowin << 4);
    *(i32x4*)&Wd1[addr] = *(i32x4*)d1;
    *(i32x4*)&Wd2[addr] = *(i32x4*)d2;
  }
}

// input_mv[r][h*8+i] = sum_d emb[x[r]][d] * Win[h][d][i]; one block = 4 rows
__global__ __launch_bounds__(256) void k_input_mv(const int* __restrict__ x,
                                                  const float* __restrict__ emb,
                                                  const float* __restrict__ Win,
                                                  float* __restrict__ out) {
  __shared__ float se[4][EMB];
  int r0 = blockIdx.x * 4;
  int t = threadIdx.x;
  for (int rr = 0; rr < 4; ++rr) {
    int tok = x[r0 + rr];
    se[rr][t] = emb[(size_t)tok * EMB + t];
  }
  __syncthreads();
  float acc[4][8];
#pragma unroll
  for (int rr = 0; rr < 4; ++rr)
#pragma unroll
    for (int i = 0; i < 8; ++i) acc[rr][i] = 0.f;
  const float* wrow = Win + (size_t)t * KDIM;
  for (int d = 0; d < EMB; ++d) {
    float4 w0 = *(const float4*)(wrow + d * 8);
    float4 w1 = *(const float4*)(wrow + d * 8 + 4);
#pragma unroll
    for (int rr = 0; rr < 4; ++rr) {
      float e = se[rr][d];
      acc[rr][0] += e * w0.x; acc[rr][1] += e * w0.y;
      acc[rr][2] += e * w0.z; acc[rr][3] += e * w0.w;
      acc[rr][4] += e * w1.x; acc[rr][5] += e * w1.y;
      acc[rr][6] += e * w1.z; acc[rr][7] += e * w1.w;
    }
  }
  for (int rr = 0; rr < 4; ++rr) {
    float4* o = (float4*)(out + (size_t)(r0 + rr) * KDIM + t * 8);
    o[0] = make_float4(acc[rr][0], acc[rr][1], acc[rr][2], acc[rr][3]);
    o[1] = make_float4(acc[rr][4], acc[rr][5], acc[rr][6], acc[rr][7]);
  }
}

// ---- free-phase bf16 split GEMM: 4 waves, 128x128 tile, BK=16, 3x16KB buffers ----
__global__ __launch_bounds__(256, 2) void k_gemm_pre(const unsigned short* __restrict__ Ahi,
                                                     const unsigned short* __restrict__ Alo,
                                                     const unsigned short* __restrict__ Bhi,
                                                     const unsigned short* __restrict__ Blo,
                                                     float* __restrict__ RF0,
                                                     float* __restrict__ RF1) {
  __shared__ __align__(16) char lds[3 * 16384];   // 3 x {Ahi 4K | Alo 4K | Bhi 4K | Blo 4K}
  const int b = blockIdx.x;                        // 512 blocks
  const int lin = (b & 7) * 64 + (b >> 3);         // XCD-chunked (512 % 8 == 0)
  const int half = lin >> 8;
  const int rest = lin & 255;
  const int tm = rest & 7, tn = rest >> 3;
  const int ktbase = half * 64;                    // kt16 units
  float* __restrict__ C = half ? RF1 : RF0;
  const int t = threadIdx.x;
  const int l = t & 63, w = t >> 6;
  const int wr = w >> 1, wc = w & 1;

  const char* aHg = (const char*)Ahi + (((size_t)tm * 128 + ktbase) << 12) + (t << 4);
  const char* aLg = (const char*)Alo + (((size_t)tm * 128 + ktbase) << 12) + (t << 4);
  const char* bHg = (const char*)Bhi + (((size_t)tn * 128 + ktbase) << 12) + (t << 4);
  const char* bLg = (const char*)Blo + (((size_t)tn * 128 + ktbase) << 12) + (t << 4);
  const int wo = w << 10;

  f32x16 acc[2][2];
#pragma unroll
  for (int i = 0; i < 2; ++i)
#pragma unroll
    for (int j = 0; j < 2; ++j) acc[i][j] = (f32x16)0.f;

  auto STAGE = [&](int bf, int kt) {
    char* lb = &lds[bf * 16384];
    size_t kb = (size_t)kt << 12;
    gload16(aHg + kb, lb + wo);
    gload16(aLg + kb, lb + 4096 + wo);
    gload16(bHg + kb, lb + 8192 + wo);
    gload16(bLg + kb, lb + 12288 + wo);
  };

  STAGE(0, 0); STAGE(1, 1);

  const int ra = wr * 64 + (l & 31);
  const int rb = wc * 64 + (l & 31);
  const int cho = (l >> 5) << 11;
  int cur = 0;
  for (int kt = 0; kt < 64; ++kt) {
    int pf = cur + 2; if (pf >= 3) pf -= 3;
    if (kt < 63) { asm volatile("s_waitcnt vmcnt(4)" ::: "memory"); }
    else         { asm volatile("s_waitcnt vmcnt(0)" ::: "memory"); }
    __builtin_amdgcn_s_barrier();
    const char* lb = &lds[cur * 16384];
    short8 ah[2], al[2], bh[2], bl[2];
#pragma unroll
    for (int mi = 0; mi < 2; ++mi) {
      int off = cho + ((ra + mi * 32) << 4);
      ah[mi] = *(const short8*)(lb + off);
      al[mi] = *(const short8*)(lb + 4096 + off);
    }
#pragma unroll
    for (int nj = 0; nj < 2; ++nj) {
      int off = cho + ((rb + nj * 32) << 4);
      bh[nj] = *(const short8*)(lb + 8192 + off);
      bl[nj] = *(const short8*)(lb + 12288 + off);
    }
    if (kt + 2 < 64) STAGE(pf, kt + 2);
    __builtin_amdgcn_s_setprio(1);
#pragma unroll
    for (int mi = 0; mi < 2; ++mi)
#pragma unroll
      for (int nj = 0; nj < 2; ++nj) {
        acc[mi][nj] = __builtin_amdgcn_mfma_f32_32x32x16_bf16(ah[mi], bh[nj], acc[mi][nj], 0, 0, 0);
        acc[mi][nj] = __builtin_amdgcn_mfma_f32_32x32x16_bf16(ah[mi], bl[nj], acc[mi][nj], 0, 0, 0);
        acc[mi][nj] = __builtin_amdgcn_mfma_f32_32x32x16_bf16(al[mi], bh[nj], acc[mi][nj], 0, 0, 0);
      }
    __builtin_amdgcn_s_setprio(0);
    cur = (cur == 2) ? 0 : cur + 1;
  }

  const int rg0 = tm * 128 + wr * 64 + ((l >> 5) << 2);
  const int cg0 = tn * 128 + wc * 64 + (l & 31);
#pragma unroll
  for (int mi = 0; mi < 2; ++mi)
#pragma unroll
    for (int nj = 0; nj < 2; ++nj) {
      f32x16 v = acc[mi][nj];
#pragma unroll
      for (int g = 0; g < 16; ++g) {
        int rr = (g & 3) + ((g >> 2) << 3);
        C[(size_t)(rg0 + mi * 32 + rr) * NCOL + cg0 + nj * 32] = v[g];
      }
    }
}

// ---- i8 digit GEMM (logits): 4 waves, 128x128 tile, BK=32, 3x16KB buffers ----
__global__ __launch_bounds__(256, 2) void k_gemm_i8(const char* __restrict__ Ad1,
                                                    const char* __restrict__ Ad2,
                                                    const char* __restrict__ Bd1,
                                                    const char* __restrict__ Bd2,
                                                    const float* __restrict__ sA,
                                                    const float* __restrict__ sB,
                                                    float* __restrict__ C) {
  __shared__ __align__(16) char lds[3 * 16384];
  const int b = blockIdx.x;                       // 2000 blocks
  const int lin = (b & 7) * 250 + (b >> 3);       // XCD-chunked (2000 % 8 == 0)
  const int tm = lin & 7, tn = lin >> 3;
  const int t = threadIdx.x;
  const int l = t & 63, w = t >> 6;
  const int wr = w >> 1, wc = w & 1;

  const char* a1g = Ad1 + (((size_t)tm * 64) << 12) + (t << 4);
  const char* a2g = Ad2 + (((size_t)tm * 64) << 12) + (t << 4);
  const char* b1g = Bd1 + (((size_t)tn * 64) << 12) + (t << 4);
  const char* b2g = Bd2 + (((size_t)tn * 64) << 12) + (t << 4);
  const int wo = w << 10;

  i32x16 acc1[2][2], acc2[2][2];
#pragma unroll
  for (int i = 0; i < 2; ++i)
#pragma unroll
    for (int j = 0; j < 2; ++j) { acc1[i][j] = (i32x16)0; acc2[i][j] = (i32x16)0; }

  auto STAGE = [&](int bf, int kt) {
    char* lb = &lds[bf * 16384];
    size_t kb = (size_t)kt << 12;
    gload16(a1g + kb, lb + wo);
    gload16(a2g + kb, lb + 4096 + wo);
    gload16(b1g + kb, lb + 8192 + wo);
    gload16(b2g + kb, lb + 12288 + wo);
  };

  STAGE(0, 0); STAGE(1, 1);

  const int ra = wr * 64 + (l & 31);
  const int rb = wc * 64 + (l & 31);
  const int kqo = (l >> 5) << 11;
  int cur = 0;
  for (int kt = 0; kt < 64; ++kt) {
    int pf = cur + 2; if (pf >= 3) pf -= 3;
    if (kt < 63) { asm volatile("s_waitcnt vmcnt(4)" ::: "memory"); }
    else         { asm volatile("s_waitcnt vmcnt(0)" ::: "memory"); }
    __builtin_amdgcn_s_barrier();
    const char* lb = &lds[cur * 16384];
    i32x4 a1[2], a2[2], b1[2], b2[2];
#pragma unroll
    for (int mi = 0; mi < 2; ++mi) {
      int off = kqo + ((ra + mi * 32) << 4);
      a1[mi] = *(const i32x4*)(lb + off);
      a2[mi] = *(const i32x4*)(lb + 4096 + off);
    }
#pragma unroll
    for (int nj = 0; nj < 2; ++nj) {
      int off = kqo + ((rb + nj * 32) << 4);
      b1[nj] = *(const i32x4*)(lb + 8192 + off);
      b2[nj] = *(const i32x4*)(lb + 12288 + off);
    }
    if (kt + 2 < 64) STAGE(pf, kt + 2);
    __builtin_amdgcn_s_setprio(1);
#pragma unroll
    for (int mi = 0; mi < 2; ++mi)
#pragma unroll
      for (int nj = 0; nj < 2; ++nj) {
        acc1[mi][nj] = __builtin_amdgcn_mfma_i32_32x32x32_i8(a1[mi], b1[nj], acc1[mi][nj], 0, 0, 0);
        acc2[mi][nj] = __builtin_amdgcn_mfma_i32_32x32x32_i8(a1[mi], b2[nj], acc2[mi][nj], 0, 0, 0);
        acc2[mi][nj] = __builtin_amdgcn_mfma_i32_32x32x32_i8(a2[mi], b1[nj], acc2[mi][nj], 0, 0, 0);
      }
    __builtin_amdgcn_s_setprio(0);
    cur = (cur == 2) ? 0 : cur + 1;
  }

  const int rbase = tm * 128 + wr * 64 + ((l >> 5) << 2);
  const int cb = tn * 128 + wc * 64 + (l & 31);
#pragma unroll
  for (int mi = 0; mi < 2; ++mi)
#pragma unroll
    for (int nj = 0; nj < 2; ++nj) {
      float sBv = sB[cb + nj * 32] * (1.f / 16384.f);
#pragma unroll
      for (int g = 0; g < 16; ++g) {
        int rr = (g & 3) + ((g >> 2) << 3);
        int row = rbase + mi * 32 + rr;
        float c1 = sA[row] * sBv;
        C[(size_t)row * VOCAB + cb + nj * 32] =
            fmaf((float)acc2[mi][nj][g], c1 * (1.f / 128.f), (float)acc1[mi][nj][g] * c1);
      }
    }
}

// h <- h - 0.1*(h - drho(h)*(inmv*sq + rec_prev*sq + fwd_next))
// FIRST=1: RF == 0 exactly (h0=0 => rho=0) -> skip RF reads (bit-identical).
// LAST=0: emit bf16 hi/lo planes; LAST=1: per-row scale + i8 digits
template <int LAST, int FIRST>
__global__ __launch_bounds__(256) void k_update(float* __restrict__ Hb, const float* __restrict__ Imv,
                                                const float* __restrict__ RF0, const float* __restrict__ RF1,
                                                unsigned short* __restrict__ Hhi,
                                                unsigned short* __restrict__ Hlo,
                                                float* __restrict__ sA,
                                                char* __restrict__ Ad1,
                                                char* __restrict__ Ad2,
                                                int big) {
  __shared__ float red[256];
  int tix = threadIdx.x;
  int idx = blockIdx.x * 256 + tix;
  int r = idx >> 8;
  int c = (idx & 255) << 3;
  int m = r & (LLEN - 1);
  const size_t base = (size_t)r * KDIM + c;
  float h[8], f[8];
  *(float4*)&h[0] = *(const float4*)(Hb + base);
  *(float4*)&h[4] = *(const float4*)(Hb + base + 4);
  float4 i0 = *(const float4*)(Imv + base);
  float4 i1 = *(const float4*)(Imv + base + 4);
  f[0] = i0.x; f[1] = i0.y; f[2] = i0.z; f[3] = i0.w;
  f[4] = i1.x; f[5] = i1.y; f[6] = i1.z; f[7] = i1.w;
#pragma unroll
  for (int j = 0; j < 8; ++j) f[j] *= ((0xE8 >> j) & 1) ? -1.f : 1.f;
  if (!FIRST) {
    if (m >= 1) {
      const float* rp0 = RF0 + (size_t)(r - 1) * NCOL + c;
      const float* rp1 = RF1 + (size_t)(r - 1) * NCOL + c;
#pragma unroll
      for (int j = 0; j < 8; ++j)
        f[j] += (rp0[j] + rp1[j]) * (((0xE8 >> j) & 1) ? -1.f : 1.f);
    }
    if (m < LLEN - 1) {
      const float* rn0 = RF0 + (size_t)(r + 1) * NCOL + KDIM + c;
      const float* rn1 = RF1 + (size_t)(r + 1) * NCOL + KDIM + c;
#pragma unroll
      for (int j = 0; j < 8; ++j) f[j] += rn0[j] + rn1[j];
    }
  }
  float hn[8], av[8];
#pragma unroll
  for (int j = 0; j < 8; ++j) {
    float hv = h[j];
    float dr = (hv > 0.f && hv < 1.f) ? 1.f : ((hv == 0.f || hv == 1.f) ? 0.5f : 0.f);
    hn[j] = hv - 0.1f * (hv - dr * f[j]);
  }
  *(float4*)(Hb + base) = make_float4(hn[0], hn[1], hn[2], hn[3]);
  *(float4*)(Hb + base + 4) = make_float4(hn[4], hn[5], hn[6], hn[7]);
  if (!LAST) {
    short8 h8, l8;
#pragma unroll
    for (int j = 0; j < 8; ++j) {
      float a = clipf(hn[j]);
      unsigned short hi = f2bf(a);
      h8[j] = (short)hi;
      l8[j] = (short)f2bf(a - bf2f(hi));
    }
    size_t off = bfoff(r >> 7, c, r);
    *(short8*)&Hhi[off] = h8;
    *(short8*)&Hlo[off] = l8;
  } else {
    if (!big) return;
#pragma unroll
    for (int j = 0; j < 8; ++j) av[j] = hn[j] * (((0xE8 >> j) & 1) ? -1.f : 1.f);
    float lm = 0.f;
#pragma unroll
    for (int j = 0; j < 8; ++j) lm = fmaxf(lm, fabsf(av[j]));
    red[tix] = lm; __syncthreads();
    for (int s = 128; s; s >>= 1) { if (tix < s) red[tix] = fmaxf(red[tix], red[tix + s]); __syncthreads(); }
    float mx = fmaxf(red[0], 1e-20f);
    float inv = dig_inv(mx);
    if (tix == 0) sA[r] = exp2f((float)(ilogbf(mx) + 2));
    char d1[8], d2[8];
#pragma unroll
    for (int j = 0; j < 8; ++j) {
      float tv = av[j] * inv;
      float f1 = rintf(tv);
      d1[j] = (char)(int)f1;
      d2[j] = (char)(int)rintf((tv - f1) * 128.f);
    }
    size_t addr = ((size_t)((r >> 7) * 64 + (c >> 5)) << 12) + (size_t)(((c >> 4) & 1) << 11)
                + ((r & 127) << 4) + (c & 15);
    *(uint64_t*)&Ad1[addr] = *(uint64_t*)d1;
    *(uint64_t*)&Ad2[addr] = *(uint64_t*)d2;
  }
}

// ---- fallback logits GEMM (in-kernel bf16 conversion), used if ws too small ----
template <int AMODE>
__global__ __launch_bounds__(256) void k_gemm_split(const float* __restrict__ A,
                                                    const float* __restrict__ B,
                                                    float* __restrict__ C, int ldc) {
  __shared__ unsigned short Ah[128 * 32], Al[128 * 32];
  __shared__ unsigned short Bh[128 * 32], Bl[128 * 32];
  const int t = threadIdx.x;
  const int row0 = blockIdx.y * 128, col0 = blockIdx.x * 128;
  const int l = t & 63, w = t >> 6;
  const int wr = w >> 1, wc = w & 1;
  const int sr = t >> 3;
  const int cc = (t & 7) << 2;
  const int chunkb = cc >> 3;
  const int halfo = (cc >> 2) & 1;
  f32x4 acc[4][4];
#pragma unroll
  for (int i = 0; i < 4; ++i)
#pragma unroll
    for (int j = 0; j < 4; ++j) acc[i][j] = (f32x4)0.f;
  const float sA0 = 1.f;
  const float sA1 = (cc & 4) ? -1.f : 1.f;
  const float sA2 = sA1;
  const float sA3 = -1.f;
  for (int k0 = 0; k0 < KDIM; k0 += 32) {
    float4 va[4], vb[4];
#pragma unroll
    for (int i = 0; i < 4; ++i) {
      va[i] = *(const float4*)(A + (size_t)(row0 + sr + i * 32) * KDIM + k0 + cc);
      vb[i] = *(const float4*)(B + (size_t)(col0 + sr + i * 32) * KDIM + k0 + cc);
    }
    __syncthreads();
#pragma unroll
    for (int i = 0; i < 4; ++i) {
      int row = sr + i * 32;
      int idx = row * 32 + ((chunkb ^ (row & 3)) << 3) + (halfo << 2);
      float4 a = va[i];
      if (AMODE == 0) {
        a.x = clipf(a.x); a.y = clipf(a.y); a.z = clipf(a.z); a.w = clipf(a.w);
      } else {
        a.x *= sA0; a.y *= sA1; a.z *= sA2; a.w *= sA3;
      }
      ushort4 h4, l4;
      h4.x = f2bf(a.x); l4.x = f2bf(a.x - bf2f(h4.x));
      h4.y = f2bf(a.y); l4.y = f2bf(a.y - bf2f(h4.y));
      h4.z = f2bf(a.z); l4.z = f2bf(a.z - bf2f(h4.z));
      h4.w = f2bf(a.w); l4.w = f2bf(a.w - bf2f(h4.w));
      *(ushort4*)&Ah[idx] = h4;
      *(ushort4*)&Al[idx] = l4;
      float4 bb = vb[i];
      h4.x = f2bf(bb.x); l4.x = f2bf(bb.x - bf2f(h4.x));
      h4.y = f2bf(bb.y); l4.y = f2bf(bb.y - bf2f(h4.y));
      h4.z = f2bf(bb.z); l4.z = f2bf(bb.z - bf2f(h4.z));
      h4.w = f2bf(bb.w); l4.w = f2bf(bb.w - bf2f(h4.w));
      *(ushort4*)&Bh[idx] = h4;
      *(ushort4*)&Bl[idx] = l4;
    }
    __syncthreads();
    short8 ah[4], al[4], bh[4], bl[4];
#pragma unroll
    for (int mi = 0; mi < 4; ++mi) {
      int ar = wr * 64 + mi * 16 + (l & 15);
      int kc = (l >> 4) ^ (ar & 3);
      ah[mi] = *(short8*)&Ah[ar * 32 + kc * 8];
      al[mi] = *(short8*)&Al[ar * 32 + kc * 8];
      int br = wc * 64 + mi * 16 + (l & 15);
      int kb = (l >> 4) ^ (br & 3);
      bh[mi] = *(short8*)&Bh[br * 32 + kb * 8];
      bl[mi] = *(short8*)&Bl[br * 32 + kb * 8];
    }
#pragma unroll
    for (int mi = 0; mi < 4; ++mi)
#pragma unroll
      for (int ni = 0; ni < 4; ++ni) {
        acc[mi][ni] = __builtin_amdgcn_mfma_f32_16x16x32_bf16(ah[mi], bh[ni], acc[mi][ni], 0, 0, 0);
        acc[mi][ni] = __builtin_amdgcn_mfma_f32_16x16x32_bf16(ah[mi], bl[ni], acc[mi][ni], 0, 0, 0);
        acc[mi][ni] = __builtin_amdgcn_mfma_f32_16x16x32_bf16(al[mi], bh[ni], acc[mi][ni], 0, 0, 0);
      }
  }
#pragma unroll
  for (int mi = 0; mi < 4; ++mi)
#pragma unroll
    for (int ni = 0; ni < 4; ++ni) {
      int rg = row0 + wr * 64 + mi * 16 + (l >> 4) * 4;
      int cg = col0 + wc * 64 + ni * 16 + (l & 15);
#pragma unroll
      for (int j = 0; j < 4; ++j)
        C[(size_t)(rg + j) * ldc + cg] = acc[mi][ni][j];
    }
}

extern "C" void kernel_launch(void* const* d_in, const int* in_sizes, int n_in,
                              void* d_out, int out_size, void* d_ws, size_t ws_size,
                              hipStream_t stream) {
  const int*   x    = (const int*)d_in[0];
  const float* emb  = (const float*)d_in[1];
  const float* Win  = (const float*)d_in[2];
  const float* Wrec = (const float*)d_in[3];
  const float* Wout = (const float*)d_in[4];
  float* logits = (float*)d_out;

  char* base = (char*)d_ws;
  const size_t MB = 1ull << 20;
  float* Hbuf = (float*)(base + 0);
  float* Imv  = (float*)(base + 8 * MB);
  float* RF0  = (float*)(base + 16 * MB);
  float* RF1  = (float*)(base + 32 * MB);
  unsigned short* Hhi = (unsigned short*)(base + 48 * MB);
  unsigned short* Hlo = (unsigned short*)(base + 52 * MB);
  unsigned short* Mhi = (unsigned short*)(base + 56 * MB);
  unsigned short* Mlo = (unsigned short*)(base + 72 * MB);
  float* sA  = (float*)(base + 88 * MB);                       // 4 KB
  float* sB  = (float*)(base + 88 * MB + 4096);                // 128 KB
  char* Wd1  = base + 88 * MB + 160 * 1024;
  char* Wd2  = Wd1 + (size_t)VOCAB * KDIM;
  // A digits reuse the MRT space (MRT last read by final k_gemm_pre, before k_update<1>)
  char* Ad1  = (char*)Mhi;
  char* Ad2  = (char*)Mlo;

  const size_t need = (size_t)(Wd2 - base) + (size_t)VOCAB * KDIM;
  const bool big = ws_size >= need;

  hipMemsetAsync(Hbuf, 0, 8 * MB, stream);
  k_build_mrt_split<<<32768, 256, 0, stream>>>(Wrec, Mhi, Mlo);
  k_input_mv<<<256, 256, 0, stream>>>(x, emb, Win, Imv);
  if (big) {
    k_dig_wout<<<8000, 256, 0, stream>>>(Wout, sB, Wd1, Wd2);
  }

  // it = 0: RF is exactly 0 (h0 = 0) -> skip the GEMM entirely (bit-identical)
  k_update<0, 1><<<1024, 256, 0, stream>>>(Hbuf, Imv, RF0, RF1, Hhi, Hlo, sA, Ad1, Ad2, big);
  for (int it = 1; it < 5; ++it) {
    k_gemm_pre<<<512, 256, 0, stream>>>(Hhi, Hlo, Mhi, Mlo, RF0, RF1);
    if (it < 4) k_update<0, 0><<<1024, 256, 0, stream>>>(Hbuf, Imv, RF0, RF1, Hhi, Hlo, sA, Ad1, Ad2, big);
    else        k_update<1, 0><<<1024, 256, 0, stream>>>(Hbuf, Imv, RF0, RF1, Hhi, Hlo, sA, Ad1, Ad2, big);
  }

  if (big) {
    k_gemm_i8<<<2000, 256, 0, stream>>>(Ad1, Ad2, Wd1, Wd2, sA, sB, logits);
  } else {
    k_gemm_split<1><<<dim3(VOCAB / 128, NROWS / 128), 256, 0, stream>>>(Hbuf, Wout, logits, VOCAB);
  }
}